// Round 1
// baseline (85.881 us; speedup 1.0000x reference)
//
#include <hip/hip_runtime.h>
#include <math.h>

#define TPB 256
#define JT 2        // j-values per thread
#define IB 64
#define EPSF 1e-15f

// Fused prep + O(n^2) pair kernel, 2 j-columns per thread.
// Rs = (g1+log y)/(h*sqrt(2 ln 2)) so exp(-0.5*((R_i-R_j)/h)^2) = exp2(-dr^2).
// A_j = sum_i d_i*e;  L*Phi = 0.5*L + copysign(L,dr)*(0.5-u),
// u = upper-tail Q(|dr_true|) via A&S 7.1.25 3-term erfc (|eps|<=2.5e-5),
// reusing the SAME exp2. The 0.5*sum(L) over this block's span is folded in
// once (spans partition i, so the block sum telescopes to 0.5*sum_all L).
// launch_bounds(256,4): <=128 VGPR so the unroll-4 body stays in registers
// (previous (256,8) forced a 64-VGPR cap on a body with ~90 live values).
__global__ __launch_bounds__(TPB, 4) void pair_kernel(
    const float* __restrict__ m_z, const float* __restrict__ y,
    const float* __restrict__ delta, float2* __restrict__ P,
    float* __restrict__ out, float inv_hk, int n, int span) {
    __shared__ float4 sRd[128];   // {R_2k, R_2k+1, d_2k, d_2k+1}
    __shared__ float2 sL2[128];   // {L_2k, L_2k+1}
    __shared__ float sLtot;
    const int tid = threadIdx.x;
    const int j0 = blockIdx.x * (TPB * JT) + tid;
    const int j1 = j0 + TPB;
    const float2* __restrict__ mz2 = (const float2*)m_z;

    const float2 gj0 = mz2[j0];
    const float2 gj1 = mz2[j1];
    const float Rj0 = (gj0.x + __logf(y[j0])) * inv_hk;
    const float Rj1 = (gj1.x + __logf(y[j1])) * inv_hk;

    // prep this block's i-span into LDS (span <= 256)
    const int ibase = blockIdx.y * span;
    if (tid < span) {
        const int i = ibase + tid;
        const float2 g = mz2[i];
        float* s = (float*)sRd;
        const int pk = tid >> 1, hf = tid & 1;
        s[4 * pk + hf]     = (g.x + __logf(y[i])) * inv_hk;
        s[4 * pk + 2 + hf] = delta[i];
        ((float*)sL2)[tid] = __expf(g.y - g.x);
    }
    __syncthreads();
    if (tid < 64) {  // wave 0: sum L over the span
        float s = 0.0f;
        for (int t = tid; t < span; t += 64) s += ((float*)sL2)[t];
        for (int o = 32; o > 0; o >>= 1) s += __shfl_down(s, o, 64);
        if (tid == 0) sLtot = s;
    }
    __syncthreads();
    if (j0 == 0 && blockIdx.y == 0) out[0] = 0.0f;  // harness poisons d_out

    const float hlt = 0.5f * sLtot;
    // acc[jcol][i-parity]
    float a00 = 0.0f, a01 = 0.0f, b00 = hlt,  b01 = 0.0f;
    float a10 = 0.0f, a11 = 0.0f, b10 = hlt,  b11 = 0.0f;
    const int m = span >> 1;
#pragma unroll 4
    for (int k = 0; k < m; ++k) {
        const float4 rd = sRd[k];                 // broadcast LDS reads,
        const float2 ll = sL2[k];                 // shared by both j-columns
        const float dx0 = rd.x - Rj0;             // i = 2k
        const float dx1 = rd.x - Rj1;
        const float dy0 = rd.y - Rj0;             // i = 2k+1
        const float dy1 = rd.y - Rj1;
        const float ex0 = __builtin_amdgcn_exp2f(-(dx0 * dx0));  // exp(-drt^2/2)
        const float ex1 = __builtin_amdgcn_exp2f(-(dx1 * dx1));
        const float ey0 = __builtin_amdgcn_exp2f(-(dy0 * dy0));
        const float ey1 = __builtin_amdgcn_exp2f(-(dy1 * dy1));
        const float tx0 = __builtin_amdgcn_rcpf(fmaf(0.3916993f, fabsf(dx0), 1.0f));
        const float tx1 = __builtin_amdgcn_rcpf(fmaf(0.3916993f, fabsf(dx1), 1.0f));
        const float ty0 = __builtin_amdgcn_rcpf(fmaf(0.3916993f, fabsf(dy0), 1.0f));
        const float ty1 = __builtin_amdgcn_rcpf(fmaf(0.3916993f, fabsf(dy1), 1.0f));
        const float ux0 = tx0 * fmaf(tx0, fmaf(tx0, 0.3739278f, -0.0479399f), 0.1740121f) * ex0;
        const float ux1 = tx1 * fmaf(tx1, fmaf(tx1, 0.3739278f, -0.0479399f), 0.1740121f) * ex1;
        const float uy0 = ty0 * fmaf(ty0, fmaf(ty0, 0.3739278f, -0.0479399f), 0.1740121f) * ey0;
        const float uy1 = ty1 * fmaf(ty1, fmaf(ty1, 0.3739278f, -0.0479399f), 0.1740121f) * ey1;
        a00 = fmaf(rd.z, ex0, a00);
        a10 = fmaf(rd.z, ex1, a10);
        a01 = fmaf(rd.w, ey0, a01);
        a11 = fmaf(rd.w, ey1, a11);
        b00 = fmaf(copysignf(ll.x, dx0), 0.5f - ux0, b00);
        b10 = fmaf(copysignf(ll.x, dx1), 0.5f - ux1, b10);
        b01 = fmaf(copysignf(ll.y, dy0), 0.5f - uy0, b01);
        b11 = fmaf(copysignf(ll.y, dy1), 0.5f - uy1, b11);
    }
    P[(size_t)blockIdx.y * n + j0] = make_float2(a00 + a01, b00 + b01);
    P[(size_t)blockIdx.y * n + j1] = make_float2(a10 + a11, b10 + b11);
}

// out = (1/n) * sum_j d_j * (R_j - g2_j - log(c1*A_j + eps) + log(invn*B_j + eps))
__global__ __launch_bounds__(TPB) void finalize_kernel(
    const float2* __restrict__ P, const float* __restrict__ m_z,
    const float* __restrict__ y, const float* __restrict__ delta,
    float* __restrict__ out, float c1, float invn, int n) {
    const int j = blockIdx.x * TPB + threadIdx.x;
    float sa = 0.0f, sb = 0.0f;
    for (int b = 0; b < IB; ++b) {               // coalesced float2 reads
        const float2 v = P[(size_t)b * n + j];
        sa += v.x;
        sb += v.y;
    }
    const float d = delta[j];
    const float R = m_z[2 * j] + __logf(y[j]);
    float term = d * (R - m_z[2 * j + 1] - __logf(fmaf(c1, sa, EPSF))
                                         + __logf(fmaf(invn, sb, EPSF)));
    for (int o = 32; o > 0; o >>= 1) term += __shfl_down(term, o, 64);
    __shared__ float wsum[TPB / 64];
    if ((threadIdx.x & 63) == 0) wsum[threadIdx.x >> 6] = term;
    __syncthreads();
    if (threadIdx.x == 0) {
        float ssum = 0.0f;
        for (int w = 0; w < TPB / 64; ++w) ssum += wsum[w];
        atomicAdd(out, ssum * invn);
    }
}

extern "C" void kernel_launch(void* const* d_in, const int* in_sizes, int n_in,
                              void* d_out, int out_size, void* d_ws, size_t ws_size,
                              hipStream_t stream) {
    const float* m_z   = (const float*)d_in[0];   // (n,2)
    const float* y     = (const float*)d_in[1];   // (n,1)
    const float* delta = (const float*)d_in[2];   // (n,1)
    float* out = (float*)d_out;
    const int n = in_sizes[1];                    // 8192

    float2* P = (float2*)d_ws;                    // IB * n * 8 B = 4 MB

    const double h = 1.3 * pow((double)n, -0.2);
    const double k = 1.1774100225154747;          // sqrt(2 ln 2)
    const float inv_hk = (float)(1.0 / (h * k));
    const float c1 = (float)(0.3989422804014327 / ((double)n * h)); // INV_SQRT_2PI/(n*h)
    const float invn = 1.0f / (float)n;
    const int span = n / IB;                      // 128

    const int nblkx = n / (TPB * JT);             // 16
    dim3 grid(nblkx, IB);                         // 1024 blocks = 4/CU
    pair_kernel<<<grid, TPB, 0, stream>>>(m_z, y, delta, P, out, inv_hk, n, span);

    const int nblk = (n + TPB - 1) / TPB;         // 32
    finalize_kernel<<<nblk, TPB, 0, stream>>>(P, m_z, y, delta, out, c1, invn, n);
}